// Round 1
// baseline (877.327 us; speedup 1.0000x reference)
//
#include <hip/hip_runtime.h>
#include <math.h>

#define NATOMS 65536

__constant__ int c_offs[12] = {0,1536,9728,26112,50688,62976,64000,64512,65024,65280,65408,65536};

struct Adj { const int* p[10]; };

__device__ __forceinline__ int seg_of(int row) {
    int s = 0;
#pragma unroll
    for (int i = 1; i <= 10; ++i) s += (row >= c_offs[i]) ? 1 : 0;
    return s;
}

// ---------------- weight assembly ----------------
// W1c[11][160][256]: k<75 -> (seg0? w0 : wself[d-1]); 75<=k<150 -> (seg0? 0 : wneigh[d-1]); else 0
__global__ void asm_w1(const float* __restrict__ w0, const float* __restrict__ wself,
                       const float* __restrict__ wneigh, float* __restrict__ W1c) {
    int idx = blockIdx.x * 256 + threadIdx.x;
    if (idx >= 11*160*256) return;
    int n = idx & 255;
    int k = (idx >> 8) % 160;
    int s = idx / (160*256);
    float v = 0.f;
    if (k < 75) v = (s == 0) ? w0[k*256 + n] : wself[((s-1)*75 + k)*256 + n];
    else if (k < 150 && s > 0) v = wneigh[((s-1)*75 + (k-75))*256 + n];
    W1c[idx] = v;
}

// W2c[11][512][256]: k<256 -> (seg0? w0 : wself[d-1]); k>=256 -> (seg0? 0 : wneigh[d-1])
__global__ void asm_w2(const float* __restrict__ w0, const float* __restrict__ wself,
                       const float* __restrict__ wneigh, float* __restrict__ W2c) {
    int idx = blockIdx.x * 256 + threadIdx.x;
    if (idx >= 11*512*256) return;
    int n = idx & 255;
    int k = (idx >> 8) & 511;
    int s = idx / (512*256);
    float v = 0.f;
    if (k < 256) v = (s == 0) ? w0[k*256 + n] : wself[((s-1)*256 + k)*256 + n];
    else if (s > 0) v = wneigh[((s-1)*256 + (k-256))*256 + n];
    W2c[idx] = v;
}

// ---------------- X1 = [x | sum_neigh(x)] padded to 160 cols ----------------
__global__ void build_x1(const float* __restrict__ xf, float* __restrict__ X1, Adj adj) {
    int idx = blockIdx.x * 256 + threadIdx.x;   // 65536*160 exact
    int r = idx / 160;
    int c = idx - r * 160;
    int s = seg_of(r);
    float v = 0.f;
    if (c < 75) {
        v = xf[(size_t)r*75 + c];
    } else if (c < 150 && s > 0) {
        int loc = r - c_offs[s];
        const int* ap = adj.p[s-1] + (size_t)loc * s;
        float sum = 0.f;
        for (int j = 0; j < s; ++j) sum += xf[(size_t)ap[j]*75 + (c-75)];
        v = sum;
    }
    X1[(size_t)r*160 + c] = v;
}

// ---------------- graph pool (elementwise max over self+neighbors), width 256 ----------------
__global__ __launch_bounds__(256) void pool_k(const float* __restrict__ H, float* __restrict__ P, Adj adj) {
    int idx = blockIdx.x * 256 + threadIdx.x;   // 65536*64 exact
    int r = idx >> 6;
    int c = (idx & 63) << 2;
    int s = seg_of(r);
    float4 v = *(const float4*)(H + (size_t)r*256 + c);
    if (s > 0) {
        int loc = r - c_offs[s];
        const int* ap = adj.p[s-1] + (size_t)loc * s;
        for (int j = 0; j < s; ++j) {
            float4 u = *(const float4*)(H + (size_t)ap[j]*256 + c);
            v.x = fmaxf(v.x,u.x); v.y = fmaxf(v.y,u.y);
            v.z = fmaxf(v.z,u.z); v.w = fmaxf(v.w,u.w);
        }
    }
    *(float4*)(P + (size_t)r*256 + c) = v;
}

// ---------------- neighbor-sum of pooled features, width 256 ----------------
__global__ __launch_bounds__(256) void nbsum_k(const float* __restrict__ P, float* __restrict__ NB, Adj adj) {
    int idx = blockIdx.x * 256 + threadIdx.x;   // 65536*64 exact
    int r = idx >> 6;
    int c = (idx & 63) << 2;
    int s = seg_of(r);
    float4 v = make_float4(0.f,0.f,0.f,0.f);
    if (s > 0) {
        int loc = r - c_offs[s];
        const int* ap = adj.p[s-1] + (size_t)loc * s;
        for (int j = 0; j < s; ++j) {
            float4 u = *(const float4*)(P + (size_t)ap[j]*256 + c);
            v.x += u.x; v.y += u.y; v.z += u.z; v.w += u.w;
        }
    }
    *(float4*)(NB + (size_t)r*256 + c) = v;
}

// ---------------- segment-selected fp32 GEMM, fused bias+relu+bn ----------------
// C[M x N] = bn(relu(A @ Wc[seg] + bias[seg]));  A cols [0,ksplit) from A0, [ksplit,K) from A1
__global__ __launch_bounds__(256)
void gemm_seg(const float* __restrict__ A0, const float* __restrict__ A1, int ksplit, int lda,
              const float* __restrict__ Wc, int wstride,
              const float* __restrict__ bias, int bstride,
              const float* __restrict__ bng, const float* __restrict__ bnb,
              const float* __restrict__ bnm, const float* __restrict__ bnv,
              float* __restrict__ C, int N, int K)
{
    __shared__ float As[16][132];   // [k][m], padded row
    __shared__ float Bs[16][128];   // [k][n]
    const int t = threadIdx.x;
    const int r0 = blockIdx.x * 128;
    const int n0 = blockIdx.y * 128;
    const int seg = seg_of(r0);
    const float* W = Wc + (size_t)seg * wstride + n0;

    float acc[8][8];
#pragma unroll
    for (int i = 0; i < 8; ++i)
#pragma unroll
        for (int j = 0; j < 8; ++j) acc[i][j] = 0.f;

    const int tx = t & 15, ty = t >> 4;
    const int arow = t >> 2, acf4 = t & 3;
    const int bkk = t >> 5, bnf4 = t & 31;

    for (int k0 = 0; k0 < K; k0 += 16) {
#pragma unroll
        for (int rep = 0; rep < 2; ++rep) {
            int row = arow + rep*64;
            int kg = k0 + acf4*4;
            const float* src = (kg < ksplit)
                ? (A0 + (size_t)(r0+row)*lda + kg)
                : (A1 + (size_t)(r0+row)*lda + (kg - ksplit));
            float4 v = *(const float4*)src;
            As[acf4*4+0][row] = v.x;
            As[acf4*4+1][row] = v.y;
            As[acf4*4+2][row] = v.z;
            As[acf4*4+3][row] = v.w;
            int kk = bkk + rep*8;
            float4 w = *(const float4*)(W + (size_t)(k0+kk)*N + bnf4*4);
            *(float4*)&Bs[kk][bnf4*4] = w;
        }
        __syncthreads();
#pragma unroll
        for (int kk = 0; kk < 16; ++kk) {
            float a[8], b[8];
            *(float4*)&a[0] = *(const float4*)&As[kk][ty*8];
            *(float4*)&a[4] = *(const float4*)&As[kk][ty*8+4];
            *(float4*)&b[0] = *(const float4*)&Bs[kk][tx*8];
            *(float4*)&b[4] = *(const float4*)&Bs[kk][tx*8+4];
#pragma unroll
            for (int i = 0; i < 8; ++i)
#pragma unroll
                for (int j = 0; j < 8; ++j)
                    acc[i][j] = fmaf(a[i], b[j], acc[i][j]);
        }
        __syncthreads();
    }

    float sc[8], sh[8], bb[8];
#pragma unroll
    for (int j = 0; j < 8; ++j) {
        int n = n0 + tx*8 + j;
        float s = bng[n] * rsqrtf(bnv[n] + 1e-3f);
        sc[j] = s;
        sh[j] = bnb[n] - bnm[n]*s;
        bb[j] = bias[(size_t)seg*bstride + n];
    }
#pragma unroll
    for (int i = 0; i < 8; ++i) {
        int m = r0 + ty*8 + i;
        float o[8];
#pragma unroll
        for (int j = 0; j < 8; ++j) {
            float v = acc[i][j] + bb[j];
            v = fmaxf(v, 0.f);
            o[j] = fmaf(v, sc[j], sh[j]);
        }
        float* dst = C + (size_t)m*N + n0 + tx*8;
        *(float4*)&dst[0] = *(float4*)&o[0];
        *(float4*)&dst[4] = *(float4*)&o[4];
    }
}

// ---------------- segment scatter (each segment has exactly 32 atoms) ----------------
__global__ void scatter_k(const int* __restrict__ mem, int* __restrict__ counts, int* __restrict__ slots) {
    int i = blockIdx.x * 256 + threadIdx.x;   // 65536 exact
    int s = mem[i];
    int p = atomicAdd(&counts[s], 1);
    if (p < 32) slots[s*32 + p] = i;
}

// ---------------- segment sum/max over H3[65536x512] -> fp = tanh([ssum|smax]) ----------------
__global__ __launch_bounds__(256)
void reduce_k(const float* __restrict__ H3, const int* __restrict__ counts,
              const int* __restrict__ slots, float* __restrict__ fp) {
    int s = blockIdx.x, t = threadIdx.x;
    int cnt = counts[s]; if (cnt > 32) cnt = 32;
    float s0 = 0.f, s1 = 0.f, m0 = -INFINITY, m1 = -INFINITY;
    for (int i = 0; i < cnt; ++i) {
        int a = slots[s*32 + i];
        const float* hr = H3 + (size_t)a*512;
        float v0 = hr[t], v1 = hr[t+256];
        s0 += v0; s1 += v1;
        m0 = fmaxf(m0, v0); m1 = fmaxf(m1, v1);
    }
    float* fr = fp + (size_t)s*1024;
    fr[t]       = tanhf(s0);
    fr[t+256]   = tanhf(s1);
    fr[512+t]   = tanhf(m0);
    fr[768+t]   = tanhf(m1);
}

// ---------------- logits = fp @ out_w + out_b; probs = softmax(pairs) ----------------
__global__ __launch_bounds__(256)
void final_k(const float* __restrict__ fp, const float* __restrict__ out_w,
             const float* __restrict__ out_b, float* __restrict__ probs, float* __restrict__ logits) {
    __shared__ float row[1024];
    __shared__ float lg[24];
    int s = blockIdx.x, t = threadIdx.x;
    const float* fr = fp + (size_t)s*1024;
    *(float4*)&row[t*4] = *(const float4*)&fr[t*4];
    __syncthreads();
    if (t < 192) {
        int o = t >> 3;
        int k0 = (t & 7) * 128;
        float acc = 0.f;
        for (int k = 0; k < 128; ++k)
            acc = fmaf(row[k0+k], out_w[(size_t)(k0+k)*24 + o], acc);
        acc += __shfl_xor(acc, 1);
        acc += __shfl_xor(acc, 2);
        acc += __shfl_xor(acc, 4);
        if ((t & 7) == 0) lg[o] = acc + out_b[o];
    }
    __syncthreads();
    if (t < 12) {
        float l0 = lg[2*t], l1 = lg[2*t+1];
        float m = fmaxf(l0, l1);
        float e0 = expf(l0-m), e1 = expf(l1-m);
        float inv = 1.f / (e0 + e1);
        int base = s*24 + 2*t;
        probs[base]   = e0*inv;  probs[base+1]  = e1*inv;
        logits[base]  = l0;      logits[base+1] = l1;
    }
}

extern "C" void kernel_launch(void* const* d_in, const int* in_sizes, int n_in,
                              void* d_out, int out_size, void* d_ws, size_t ws_size,
                              hipStream_t stream) {
    const float* atom       = (const float*)d_in[0];
    const int*   membership = (const int*)  d_in[2];
    Adj adj;
    for (int d = 0; d < 10; ++d) adj.p[d] = (const int*)d_in[4+d];
    const float* gc1_w0     = (const float*)d_in[14];
    const float* gc1_wself  = (const float*)d_in[15];
    const float* gc1_wneigh = (const float*)d_in[16];
    const float* gc1_b      = (const float*)d_in[17];
    const float* gc2_w0     = (const float*)d_in[18];
    const float* gc2_wself  = (const float*)d_in[19];
    const float* gc2_wneigh = (const float*)d_in[20];
    const float* gc2_b      = (const float*)d_in[21];
    const float* bn1g = (const float*)d_in[22]; const float* bn1b = (const float*)d_in[23];
    const float* bn1m = (const float*)d_in[24]; const float* bn1v = (const float*)d_in[25];
    const float* bn2g = (const float*)d_in[26]; const float* bn2b = (const float*)d_in[27];
    const float* bn2m = (const float*)d_in[28]; const float* bn2v = (const float*)d_in[29];
    const float* bn3g = (const float*)d_in[30]; const float* bn3b = (const float*)d_in[31];
    const float* bn3m = (const float*)d_in[32]; const float* bn3v = (const float*)d_in[33];
    const float* dense_w = (const float*)d_in[34];
    const float* dense_b = (const float*)d_in[35];
    const float* out_w   = (const float*)d_in[36];
    const float* out_b   = (const float*)d_in[37];

    float* ws = (float*)d_ws;
    // layout (floats), with aliasing: X1 dead after GEMM1; H1 region reused by H2;
    // NB2 region reused by P2; H3 spans H1+P1 regions (both dead by then)
    float* X1  = ws;                      // 65536*160 = 10485760
    float* H1  = ws + 10485760;           // 65536*256
    float* P1  = ws + 27262976;           // 65536*256
    float* NB2 = ws + 44040192;           // 65536*256  (later P2)
    float* H2  = H1;
    float* P2  = NB2;
    float* H3  = ws + 10485760;           // 65536*512 spans H1+P1
    float* W1c = ws + 60817408;           // 11*160*256 = 450560
    float* W2c = ws + 61267968;           // 11*512*256 = 1441792
    int*   counts = (int*)(ws + 62709760);            // 2048
    int*   slots  = counts + 2048;                    // 65536

    float* outp   = (float*)d_out;
    float* probs  = outp;            // 2048*24
    float* logits = outp + 49152;    // 2048*24
    float* fp     = outp + 98304;    // 2048*1024

    // weight tables
    asm_w1<<<(11*160*256 + 255)/256, 256, 0, stream>>>(gc1_w0, gc1_wself, gc1_wneigh, W1c);
    asm_w2<<<(11*512*256 + 255)/256, 256, 0, stream>>>(gc2_w0, gc2_wself, gc2_wneigh, W2c);

    // gc1
    build_x1<<<(NATOMS*160)/256, 256, 0, stream>>>(atom, X1, adj);
    gemm_seg<<<dim3(512,2), 256, 0, stream>>>(X1, X1, 160, 160, W1c, 160*256, gc1_b, 256,
                                              bn1g, bn1b, bn1m, bn1v, H1, 256, 160);
    pool_k<<<(NATOMS*64)/256, 256, 0, stream>>>(H1, P1, adj);

    // gc2
    nbsum_k<<<(NATOMS*64)/256, 256, 0, stream>>>(P1, NB2, adj);
    gemm_seg<<<dim3(512,2), 256, 0, stream>>>(P1, NB2, 256, 256, W2c, 512*256, gc2_b, 256,
                                              bn2g, bn2b, bn2m, bn2v, H2, 256, 512);
    pool_k<<<(NATOMS*64)/256, 256, 0, stream>>>(H2, P2, adj);

    // dense
    gemm_seg<<<dim3(512,4), 256, 0, stream>>>(P2, P2, 256, 256, dense_w, 0, dense_b, 0,
                                              bn3g, bn3b, bn3m, bn3v, H3, 512, 256);

    // segment reduce + tanh -> fp
    hipMemsetAsync((void*)counts, 0, 2048*sizeof(int), stream);
    scatter_k<<<NATOMS/256, 256, 0, stream>>>(membership, counts, slots);
    reduce_k<<<2048, 256, 0, stream>>>(H3, counts, slots, fp);

    // readout
    final_k<<<2048, 256, 0, stream>>>(fp, out_w, out_b, probs, logits);
}

// Round 3
// 462.519 us; speedup vs baseline: 1.8968x; 1.8968x over previous
//
#include <hip/hip_runtime.h>
#include <hip/hip_fp16.h>
#include <math.h>

#define NATOMS 65536

typedef _Float16 f16_t;
typedef __attribute__((ext_vector_type(8))) _Float16 half8;
typedef __attribute__((ext_vector_type(4))) float f32x4;

__constant__ int c_offs[12] = {0,1536,9728,26112,50688,62976,64000,64512,65024,65280,65408,65536};

struct Adj { const int* p[10]; };

__device__ __forceinline__ int seg_of(int row) {
    int s = 0;
#pragma unroll
    for (int i = 1; i <= 10; ++i) s += (row >= c_offs[i]) ? 1 : 0;
    return s;
}

// ---------------- weight packing into MFMA B-fragment layout ----------------
// blob index: (((seg*NNT + ni)*NKB + kb)*512) + lane*8 + j
// blob[lane][j] = W[kb*32 + (lane>>4)*8 + j][ni*16 + (lane&15)]

// gc1: K=160 (75 self | 75 neigh | 10 zero-pad), N=256, 11 segs
__global__ void pack_w1(const float* __restrict__ w0, const float* __restrict__ wself,
                        const float* __restrict__ wneigh, f16_t* __restrict__ Wp) {
    int idx = blockIdx.x * 256 + threadIdx.x;      // 11*16*5*512 = 450560 exact
    int j = idx & 7, lane = (idx >> 3) & 63;
    int kb = (idx >> 9) % 5;
    int rest = idx / (512 * 5);
    int ni = rest & 15, s = rest >> 4;
    int k = kb * 32 + (lane >> 4) * 8 + j;
    int n = ni * 16 + (lane & 15);
    float v = 0.f;
    if (k < 75) v = (s == 0) ? w0[k*256 + n] : wself[((s-1)*75 + k)*256 + n];
    else if (k < 150 && s > 0) v = wneigh[((s-1)*75 + (k-75))*256 + n];
    Wp[idx] = (f16_t)v;
}

// gc2: K=512 (256 self | 256 neigh), N=256, 11 segs
__global__ void pack_w2(const float* __restrict__ w0, const float* __restrict__ wself,
                        const float* __restrict__ wneigh, f16_t* __restrict__ Wp) {
    int idx = blockIdx.x * 256 + threadIdx.x;      // 11*16*16*512 = 1441792 exact
    int j = idx & 7, lane = (idx >> 3) & 63;
    int kb = (idx >> 9) & 15;
    int rest = idx >> 13;
    int ni = rest & 15, s = rest >> 4;
    int k = kb * 32 + (lane >> 4) * 8 + j;
    int n = ni * 16 + (lane & 15);
    float v = 0.f;
    if (k < 256) v = (s == 0) ? w0[k*256 + n] : wself[((s-1)*256 + k)*256 + n];
    else if (s > 0) v = wneigh[((s-1)*256 + (k-256))*256 + n];
    Wp[idx] = (f16_t)v;
}

// dense: K=256, N=512, 1 seg
__global__ void pack_wd(const float* __restrict__ w, f16_t* __restrict__ Wp) {
    int idx = blockIdx.x * 256 + threadIdx.x;      // 32*8*512 = 131072 exact
    int j = idx & 7, lane = (idx >> 3) & 63;
    int kb = (idx >> 9) & 7;
    int ni = (idx >> 12) & 31;
    int k = kb * 32 + (lane >> 4) * 8 + j;
    int n = ni * 16 + (lane & 15);
    Wp[idx] = (f16_t)w[(size_t)k*512 + n];
}

// ---------------- X1 = [x | sum_neigh(x)] padded to 160 cols, f16 ----------------
__global__ void build_x1(const float* __restrict__ xf, f16_t* __restrict__ X1, Adj adj) {
    int idx = blockIdx.x * 256 + threadIdx.x;   // 65536*160 exact
    int r = idx / 160;
    int c = idx - r * 160;
    int s = seg_of(r);
    float v = 0.f;
    if (c < 75) {
        v = xf[(size_t)r*75 + c];
    } else if (c < 150 && s > 0) {
        int loc = r - c_offs[s];
        const int* ap = adj.p[s-1] + (size_t)loc * s;
        float sum = 0.f;
        for (int j = 0; j < s; ++j) sum += xf[(size_t)ap[j]*75 + (c-75)];
        v = sum;
    }
    X1[(size_t)r*160 + c] = (f16_t)v;
}

// ---------------- graph pool: elementwise max over self+neighbors (f16, lossless) ----------------
__global__ __launch_bounds__(256) void pool_k(const f16_t* __restrict__ H, f16_t* __restrict__ P, Adj adj) {
    int idx = blockIdx.x * 256 + threadIdx.x;   // 65536*32 exact
    int r = idx >> 5;
    int c = (idx & 31) << 3;
    int s = seg_of(r);
    const f16_t* hr = H + (size_t)r*256 + c;
    float mx[8];
#pragma unroll
    for (int e = 0; e < 8; ++e) mx[e] = (float)hr[e];
    if (s > 0) {
        int loc = r - c_offs[s];
        const int* ap = adj.p[s-1] + (size_t)loc * s;
        for (int j = 0; j < s; ++j) {
            const f16_t* ur = H + (size_t)ap[j]*256 + c;
#pragma unroll
            for (int e = 0; e < 8; ++e) mx[e] = fmaxf(mx[e], (float)ur[e]);
        }
    }
    f16_t o[8];
#pragma unroll
    for (int e = 0; e < 8; ++e) o[e] = (f16_t)mx[e];
    *(uint4*)(P + (size_t)r*256 + c) = *(uint4*)o;
}

// ---------------- neighbor-sum of pooled features (fp32 accum -> f16) ----------------
__global__ __launch_bounds__(256) void nbsum_k(const f16_t* __restrict__ P, f16_t* __restrict__ NB, Adj adj) {
    int idx = blockIdx.x * 256 + threadIdx.x;   // 65536*32 exact
    int r = idx >> 5;
    int c = (idx & 31) << 3;
    int s = seg_of(r);
    float sm[8];
#pragma unroll
    for (int e = 0; e < 8; ++e) sm[e] = 0.f;
    if (s > 0) {
        int loc = r - c_offs[s];
        const int* ap = adj.p[s-1] + (size_t)loc * s;
        for (int j = 0; j < s; ++j) {
            const f16_t* ur = P + (size_t)ap[j]*256 + c;
#pragma unroll
            for (int e = 0; e < 8; ++e) sm[e] += (float)ur[e];
        }
    }
    f16_t o[8];
#pragma unroll
    for (int e = 0; e < 8; ++e) o[e] = (f16_t)sm[e];
    *(uint4*)(NB + (size_t)r*256 + c) = *(uint4*)o;
}

// ---------------- f16 MFMA GEMM, no LDS, fused bias+relu+bn, f16 out ----------------
// C[M x N] = bn(relu(A @ W[seg] + bias[seg])); A cols [0,KSPLIT) from A0, rest from A1.
// 128x128 tile per block; 4 waves in 2x2; each wave 64x64 = 4x4 MFMA frags.
template<int K, int KSPLIT, int LDA, int N, bool SEG>
__global__ __launch_bounds__(256)
void gemm_mfma(const f16_t* __restrict__ A0, const f16_t* __restrict__ A1,
               const f16_t* __restrict__ Wp,
               const float* __restrict__ bias,
               const float* __restrict__ bng, const float* __restrict__ bnb,
               const float* __restrict__ bnm, const float* __restrict__ bnv,
               f16_t* __restrict__ C)
{
    constexpr int NKB = K / 32;
    constexpr int NNT = N / 16;
    const int t = threadIdx.x;
    const int lane = t & 63, wave = t >> 6;
    const int wm = wave >> 1, wn = wave & 1;
    const int quad = lane >> 4, l16 = lane & 15;
    const int r0 = blockIdx.x * 128;
    const int n0 = blockIdx.y * 128;
    const int seg = SEG ? seg_of(r0) : 0;

    f32x4 acc[4][4];
#pragma unroll
    for (int mi = 0; mi < 4; ++mi)
#pragma unroll
        for (int ni = 0; ni < 4; ++ni) acc[mi][ni] = (f32x4){0.f,0.f,0.f,0.f};

    size_t rowoff[4];
#pragma unroll
    for (int mi = 0; mi < 4; ++mi)
        rowoff[mi] = (size_t)(r0 + wm*64 + mi*16 + l16) * LDA + quad*8;
    size_t boff[4];
#pragma unroll
    for (int ni = 0; ni < 4; ++ni) {
        int nt = (n0 >> 4) + wn*4 + ni;
        boff[ni] = (size_t)(seg * NNT + nt) * NKB * 512 + lane*8;
    }

#pragma unroll
    for (int kb = 0; kb < NKB; ++kb) {
        const int kg = kb * 32;
        const f16_t* Abase = (kg < KSPLIT) ? (A0 + kg) : (A1 + (kg - KSPLIT));
        half8 a[4], b[4];
#pragma unroll
        for (int mi = 0; mi < 4; ++mi)
            a[mi] = *(const half8*)(Abase + rowoff[mi]);
#pragma unroll
        for (int ni = 0; ni < 4; ++ni)
            b[ni] = *(const half8*)(Wp + boff[ni] + (size_t)kb*512);
#pragma unroll
        for (int mi = 0; mi < 4; ++mi)
#pragma unroll
            for (int ni = 0; ni < 4; ++ni)
                acc[mi][ni] = __builtin_amdgcn_mfma_f32_16x16x32_f16(a[mi], b[ni], acc[mi][ni], 0, 0, 0);
    }

    // epilogue: C/D layout col = lane&15, row = quad*4 + reg
#pragma unroll
    for (int ni = 0; ni < 4; ++ni) {
        const int col = n0 + (wn*4 + ni)*16 + l16;
        const float scale = bng[col] * rsqrtf(bnv[col] + 1e-3f);
        const float shift = bnb[col] - bnm[col] * scale;
        const float bv = bias[(SEG ? seg*N : 0) + col];
#pragma unroll
        for (int mi = 0; mi < 4; ++mi) {
            const int rowb = r0 + wm*64 + mi*16 + quad*4;
#pragma unroll
            for (int r = 0; r < 4; ++r) {
                float v = acc[mi][ni][r] + bv;
                v = fmaxf(v, 0.f);
                v = fmaf(v, scale, shift);
                C[(size_t)(rowb + r) * N + col] = (f16_t)v;
            }
        }
    }
}

// ---------------- segment scatter (each segment has exactly 32 atoms) ----------------
__global__ void scatter_k(const int* __restrict__ mem, int* __restrict__ counts, int* __restrict__ slots) {
    int i = blockIdx.x * 256 + threadIdx.x;   // 65536 exact
    int s = mem[i];
    int p = atomicAdd(&counts[s], 1);
    if (p < 32) slots[s*32 + p] = i;
}

// ---------------- segment sum/max over H3[65536x512] f16 -> fp = tanh([ssum|smax]) ----------------
__global__ __launch_bounds__(256)
void reduce_k(const f16_t* __restrict__ H3, const int* __restrict__ counts,
              const int* __restrict__ slots, float* __restrict__ fp) {
    int s = blockIdx.x, t = threadIdx.x;
    int cnt = counts[s]; if (cnt > 32) cnt = 32;
    float s0 = 0.f, s1 = 0.f, m0 = -INFINITY, m1 = -INFINITY;
    for (int i = 0; i < cnt; ++i) {
        int a = slots[s*32 + i];
        const f16_t* hr = H3 + (size_t)a*512;
        float v0 = (float)hr[t], v1 = (float)hr[t+256];
        s0 += v0; s1 += v1;
        m0 = fmaxf(m0, v0); m1 = fmaxf(m1, v1);
    }
    float* fr = fp + (size_t)s*1024;
    fr[t]       = tanhf(s0);
    fr[t+256]   = tanhf(s1);
    fr[512+t]   = tanhf(m0);
    fr[768+t]   = tanhf(m1);
}

// ---------------- logits = fp @ out_w + out_b; probs = softmax(pairs) ----------------
__global__ __launch_bounds__(256)
void final_k(const float* __restrict__ fp, const float* __restrict__ out_w,
             const float* __restrict__ out_b, float* __restrict__ probs, float* __restrict__ logits) {
    __shared__ float row[1024];
    __shared__ float lg[24];
    int s = blockIdx.x, t = threadIdx.x;
    const float* fr = fp + (size_t)s*1024;
    *(float4*)&row[t*4] = *(const float4*)&fr[t*4];
    __syncthreads();
    if (t < 192) {
        int o = t >> 3;
        int k0 = (t & 7) * 128;
        float acc = 0.f;
        for (int k = 0; k < 128; ++k)
            acc = fmaf(row[k0+k], out_w[(size_t)(k0+k)*24 + o], acc);
        acc += __shfl_xor(acc, 1);
        acc += __shfl_xor(acc, 2);
        acc += __shfl_xor(acc, 4);
        if ((t & 7) == 0) lg[o] = acc + out_b[o];
    }
    __syncthreads();
    if (t < 12) {
        float l0 = lg[2*t], l1 = lg[2*t+1];
        float m = fmaxf(l0, l1);
        float e0 = expf(l0-m), e1 = expf(l1-m);
        float inv = 1.f / (e0 + e1);
        int base = s*24 + 2*t;
        probs[base]   = e0*inv;  probs[base+1]  = e1*inv;
        logits[base]  = l0;      logits[base+1] = l1;
    }
}

extern "C" void kernel_launch(void* const* d_in, const int* in_sizes, int n_in,
                              void* d_out, int out_size, void* d_ws, size_t ws_size,
                              hipStream_t stream) {
    const float* atom       = (const float*)d_in[0];
    const int*   membership = (const int*)  d_in[2];
    Adj adj;
    for (int d = 0; d < 10; ++d) adj.p[d] = (const int*)d_in[4+d];
    const float* gc1_w0     = (const float*)d_in[14];
    const float* gc1_wself  = (const float*)d_in[15];
    const float* gc1_wneigh = (const float*)d_in[16];
    const float* gc1_b      = (const float*)d_in[17];
    const float* gc2_w0     = (const float*)d_in[18];
    const float* gc2_wself  = (const float*)d_in[19];
    const float* gc2_wneigh = (const float*)d_in[20];
    const float* gc2_b      = (const float*)d_in[21];
    const float* bn1g = (const float*)d_in[22]; const float* bn1b = (const float*)d_in[23];
    const float* bn1m = (const float*)d_in[24]; const float* bn1v = (const float*)d_in[25];
    const float* bn2g = (const float*)d_in[26]; const float* bn2b = (const float*)d_in[27];
    const float* bn2m = (const float*)d_in[28]; const float* bn2v = (const float*)d_in[29];
    const float* bn3g = (const float*)d_in[30]; const float* bn3b = (const float*)d_in[31];
    const float* bn3m = (const float*)d_in[32]; const float* bn3v = (const float*)d_in[33];
    const float* dense_w = (const float*)d_in[34];
    const float* dense_b = (const float*)d_in[35];
    const float* out_w   = (const float*)d_in[36];
    const float* out_b   = (const float*)d_in[37];

    // workspace layout in f16 elements (2B each); aliasing:
    //   H2 = H1 (H1 dead after pool1); P2 = P1 (P1 dead after gemm2);
    //   H3 takes NB2 region + free space (NB2 dead after gemm2)
    f16_t* wsb = (f16_t*)d_ws;
    f16_t* X1b  = wsb;                       // 10,485,760
    f16_t* H1b  = wsb + 10485760;            // 16,777,216
    f16_t* P1b  = wsb + 27262976;            // 16,777,216
    f16_t* NB2b = wsb + 44040192;            // 16,777,216
    f16_t* H2b  = H1b;
    f16_t* P2b  = P1b;
    f16_t* H3b  = wsb + 44040192;            // 33,554,432 (spans NB2b + free)
    f16_t* W1p  = wsb + 77594624;            // 450,560
    f16_t* W2p  = wsb + 78045184;            // 1,441,792
    f16_t* Wdp  = wsb + 79486976;            // 131,072
    int*  counts = (int*)(wsb + 79618048);   // 2048 ints
    int*  slots  = counts + 2048;            // 65536 ints

    float* outp   = (float*)d_out;
    float* probs  = outp;            // 2048*24
    float* logits = outp + 49152;    // 2048*24
    float* fp     = outp + 98304;    // 2048*1024

    // weight packing
    pack_w1<<<1760, 256, 0, stream>>>(gc1_w0, gc1_wself, gc1_wneigh, W1p);
    pack_w2<<<5632, 256, 0, stream>>>(gc2_w0, gc2_wself, gc2_wneigh, W2p);
    pack_wd<<<512,  256, 0, stream>>>(dense_w, Wdp);

    // gc1
    build_x1<<<(NATOMS*160)/256, 256, 0, stream>>>(atom, X1b, adj);
    gemm_mfma<160,160,160,256,true><<<dim3(512,2), 256, 0, stream>>>(
        X1b, X1b, W1p, gc1_b, bn1g, bn1b, bn1m, bn1v, H1b);
    pool_k<<<(NATOMS*32)/256, 256, 0, stream>>>(H1b, P1b, adj);

    // gc2
    nbsum_k<<<(NATOMS*32)/256, 256, 0, stream>>>(P1b, NB2b, adj);
    gemm_mfma<512,256,256,256,true><<<dim3(512,2), 256, 0, stream>>>(
        P1b, NB2b, W2p, gc2_b, bn2g, bn2b, bn2m, bn2v, H2b);
    pool_k<<<(NATOMS*32)/256, 256, 0, stream>>>(H2b, P2b, adj);

    // dense
    gemm_mfma<256,256,256,512,false><<<dim3(512,4), 256, 0, stream>>>(
        P2b, P2b, Wdp, dense_b, bn3g, bn3b, bn3m, bn3v, H3b);

    // segment reduce + tanh -> fp
    hipMemsetAsync((void*)counts, 0, 2048*sizeof(int), stream);
    scatter_k<<<NATOMS/256, 256, 0, stream>>>(membership, counts, slots);
    reduce_k<<<2048, 256, 0, stream>>>(H3b, counts, slots, fp);

    // readout
    final_k<<<2048, 256, 0, stream>>>(fp, out_w, out_b, probs, logits);
}

// Round 4
// 433.693 us; speedup vs baseline: 2.0229x; 1.0665x over previous
//
#include <hip/hip_runtime.h>
#include <hip/hip_fp16.h>
#include <math.h>

#define NATOMS 65536

typedef _Float16 f16_t;
typedef __attribute__((ext_vector_type(8))) _Float16 half8;
typedef __attribute__((ext_vector_type(4))) float f32x4;

__constant__ int c_offs[12] = {0,1536,9728,26112,50688,62976,64000,64512,65024,65280,65408,65536};

struct Adj { const int* p[10]; };

__device__ __forceinline__ int seg_of(int row) {
    int s = 0;
#pragma unroll
    for (int i = 1; i <= 10; ++i) s += (row >= c_offs[i]) ? 1 : 0;
    return s;
}

// ---------------- weight packing into MFMA B-fragment layout ----------------
// blob index: (((seg*NNT + ni)*NKB + kb)*512) + lane*8 + j
// blob[lane][j] = W[kb*32 + (lane>>4)*8 + j][ni*16 + (lane&15)]

// gc1: K=192 (75 self | 21 pad | 75 neigh @96 | pad), N=256, 11 segs, NKB=6
__global__ void pack_w1(const float* __restrict__ w0, const float* __restrict__ wself,
                        const float* __restrict__ wneigh, f16_t* __restrict__ Wp) {
    int idx = blockIdx.x * 256 + threadIdx.x;      // 11*16*6*512 = 540672 exact
    int j = idx & 7, lane = (idx >> 3) & 63;
    int kb = (idx >> 9) % 6;
    int rest = idx / (512 * 6);
    int ni = rest & 15, s = rest >> 4;
    int k = kb * 32 + (lane >> 4) * 8 + j;
    int n = ni * 16 + (lane & 15);
    float v = 0.f;
    if (k < 75) v = (s == 0) ? w0[k*256 + n] : wself[((s-1)*75 + k)*256 + n];
    else if (k >= 96 && k < 171 && s > 0) v = wneigh[((s-1)*75 + (k-96))*256 + n];
    Wp[idx] = (f16_t)v;
}

// gc2: K=512 (256 self | 256 neigh), N=256, 11 segs, NKB=16
__global__ void pack_w2(const float* __restrict__ w0, const float* __restrict__ wself,
                        const float* __restrict__ wneigh, f16_t* __restrict__ Wp) {
    int idx = blockIdx.x * 256 + threadIdx.x;      // 11*16*16*512 = 1441792 exact
    int j = idx & 7, lane = (idx >> 3) & 63;
    int kb = (idx >> 9) & 15;
    int rest = idx >> 13;
    int ni = rest & 15, s = rest >> 4;
    int k = kb * 32 + (lane >> 4) * 8 + j;
    int n = ni * 16 + (lane & 15);
    float v = 0.f;
    if (k < 256) v = (s == 0) ? w0[k*256 + n] : wself[((s-1)*256 + k)*256 + n];
    else if (s > 0) v = wneigh[((s-1)*256 + (k-256))*256 + n];
    Wp[idx] = (f16_t)v;
}

// dense: K=256, N=512, 1 seg, NKB=8
__global__ void pack_wd(const float* __restrict__ w, f16_t* __restrict__ Wp) {
    int idx = blockIdx.x * 256 + threadIdx.x;      // 32*8*512 = 131072 exact
    int j = idx & 7, lane = (idx >> 3) & 63;
    int kb = (idx >> 9) & 7;
    int ni = (idx >> 12) & 31;
    int k = kb * 32 + (lane >> 4) * 8 + j;
    int n = ni * 16 + (lane & 15);
    Wp[idx] = (f16_t)w[(size_t)k*512 + n];
}

// ---------------- xq = f16(atom_features) padded 75 -> 96 cols ----------------
__global__ void cvt_pad(const float* __restrict__ xf, f16_t* __restrict__ xq) {
    int idx = blockIdx.x * 256 + threadIdx.x;   // 65536*96 exact
    int r = idx / 96;
    int c = idx - r * 96;
    xq[idx] = (c < 75) ? (f16_t)xf[(size_t)r*75 + c] : (f16_t)0.f;
}

// ---------------- NBX[r] = sum_neigh xq, 96 cols, f16 gather + fp32 accum ----------------
__global__ __launch_bounds__(256) void nbsum_x(const f16_t* __restrict__ xq, f16_t* __restrict__ NBX, Adj adj) {
    int idx = blockIdx.x * 256 + threadIdx.x;   // 65536*12 exact
    int r = idx / 12;
    int cc = idx - r * 12;
    int c = cc << 3;
    int s = seg_of(r);
    float sm[8];
#pragma unroll
    for (int e = 0; e < 8; ++e) sm[e] = 0.f;
    if (s > 0) {
        int loc = r - c_offs[s];
        const int* ap = adj.p[s-1] + (size_t)loc * s;
        for (int j = 0; j < s; ++j) {
            const f16_t* ur = xq + (size_t)ap[j]*96 + c;
#pragma unroll
            for (int e = 0; e < 8; ++e) sm[e] += (float)ur[e];
        }
    }
    f16_t o[8];
#pragma unroll
    for (int e = 0; e < 8; ++e) o[e] = (f16_t)sm[e];
    *(uint4*)(NBX + (size_t)r*96 + c) = *(uint4*)o;
}

// ---------------- graph pool: elementwise max over self+neighbors (f16) ----------------
__global__ __launch_bounds__(256) void pool_k(const f16_t* __restrict__ H, f16_t* __restrict__ P, Adj adj) {
    int idx = blockIdx.x * 256 + threadIdx.x;   // 65536*32 exact
    int r = idx >> 5;
    int c = (idx & 31) << 3;
    int s = seg_of(r);
    const f16_t* hr = H + (size_t)r*256 + c;
    float mx[8];
#pragma unroll
    for (int e = 0; e < 8; ++e) mx[e] = (float)hr[e];
    if (s > 0) {
        int loc = r - c_offs[s];
        const int* ap = adj.p[s-1] + (size_t)loc * s;
        for (int j = 0; j < s; ++j) {
            const f16_t* ur = H + (size_t)ap[j]*256 + c;
#pragma unroll
            for (int e = 0; e < 8; ++e) mx[e] = fmaxf(mx[e], (float)ur[e]);
        }
    }
    f16_t o[8];
#pragma unroll
    for (int e = 0; e < 8; ++e) o[e] = (f16_t)mx[e];
    *(uint4*)(P + (size_t)r*256 + c) = *(uint4*)o;
}

// ---------------- neighbor-sum of pooled features (fp32 accum -> f16), 256 cols ----------------
__global__ __launch_bounds__(256) void nbsum_k(const f16_t* __restrict__ P, f16_t* __restrict__ NB, Adj adj) {
    int idx = blockIdx.x * 256 + threadIdx.x;   // 65536*32 exact
    int r = idx >> 5;
    int c = (idx & 31) << 3;
    int s = seg_of(r);
    float sm[8];
#pragma unroll
    for (int e = 0; e < 8; ++e) sm[e] = 0.f;
    if (s > 0) {
        int loc = r - c_offs[s];
        const int* ap = adj.p[s-1] + (size_t)loc * s;
        for (int j = 0; j < s; ++j) {
            const f16_t* ur = P + (size_t)ap[j]*256 + c;
#pragma unroll
            for (int e = 0; e < 8; ++e) sm[e] += (float)ur[e];
        }
    }
    f16_t o[8];
#pragma unroll
    for (int e = 0; e < 8; ++e) o[e] = (f16_t)sm[e];
    *(uint4*)(NB + (size_t)r*256 + c) = *(uint4*)o;
}

// ---------------- f16 MFMA GEMM, fused bias+relu+bn, LDS-staged coalesced stores ----------------
// C = bn(relu(A @ W[seg] + bias[seg])); A cols [0,KSPLIT) from A0, rest from A1.
// 128x128 tile per block; 4 waves 2x2; wave 64x64 = 4x4 frags.
// XCD swizzle: 1-D grid, all NY n-tiles of an A row-tile land on one XCD.
template<int K, int KSPLIT, int LDA, int N, int NY, bool SEG>
__global__ __launch_bounds__(256)
void gemm_mfma(const f16_t* __restrict__ A0, const f16_t* __restrict__ A1,
               const f16_t* __restrict__ Wp,
               const float* __restrict__ bias,
               const float* __restrict__ bng, const float* __restrict__ bnb,
               const float* __restrict__ bnm, const float* __restrict__ bnv,
               f16_t* __restrict__ C)
{
    constexpr int NKB = K / 32;
    constexpr int NNT = N / 16;
    __shared__ f16_t lds[128 * 136];
    const int t = threadIdx.x;
    const int lane = t & 63, wave = t >> 6;
    const int wm = wave >> 1, wn = wave & 1;
    const int quad = lane >> 4, l16 = lane & 15;
    // XCD-aware remap (8 XCDs, round-robin dispatch assumed; perf-only heuristic)
    const int id = blockIdx.x;
    const int xcd = id & 7;
    const int j = id >> 3;
    const int xi = j / NY;
    const int y  = j - xi * NY;
    const int r0 = (xi * 8 + xcd) * 128;
    const int n0 = y * 128;
    const int seg = SEG ? seg_of(r0) : 0;

    f32x4 acc[4][4];
#pragma unroll
    for (int mi = 0; mi < 4; ++mi)
#pragma unroll
        for (int ni = 0; ni < 4; ++ni) acc[mi][ni] = (f32x4){0.f,0.f,0.f,0.f};

    size_t rowoff[4];
#pragma unroll
    for (int mi = 0; mi < 4; ++mi)
        rowoff[mi] = (size_t)(r0 + wm*64 + mi*16 + l16) * LDA + quad*8;
    size_t boff[4];
#pragma unroll
    for (int ni = 0; ni < 4; ++ni) {
        int nt = (n0 >> 4) + wn*4 + ni;
        boff[ni] = (size_t)(seg * NNT + nt) * NKB * 512 + lane*8;
    }

#pragma unroll
    for (int kb = 0; kb < NKB; ++kb) {
        const int kg = kb * 32;
        const f16_t* Abase = (kg < KSPLIT) ? (A0 + kg) : (A1 + (kg - KSPLIT));
        half8 a[4], b[4];
#pragma unroll
        for (int mi = 0; mi < 4; ++mi)
            a[mi] = *(const half8*)(Abase + rowoff[mi]);
#pragma unroll
        for (int ni = 0; ni < 4; ++ni)
            b[ni] = *(const half8*)(Wp + boff[ni] + (size_t)kb*512);
#pragma unroll
        for (int mi = 0; mi < 4; ++mi)
#pragma unroll
            for (int ni = 0; ni < 4; ++ni)
                acc[mi][ni] = __builtin_amdgcn_mfma_f32_16x16x32_f16(a[mi], b[ni], acc[mi][ni], 0, 0, 0);
    }

    // epilogue: C/D layout col = lane&15, row = quad*4 + reg -> LDS tile
#pragma unroll
    for (int ni = 0; ni < 4; ++ni) {
        const int col = n0 + (wn*4 + ni)*16 + l16;
        const float scale = bng[col] * rsqrtf(bnv[col] + 1e-3f);
        const float shift = bnb[col] - bnm[col] * scale;
        const float bv = bias[(SEG ? seg*N : 0) + col];
        const int lcol = (wn*4 + ni)*16 + l16;
#pragma unroll
        for (int mi = 0; mi < 4; ++mi) {
            const int lrowb = wm*64 + mi*16 + quad*4;
#pragma unroll
            for (int r = 0; r < 4; ++r) {
                float v = acc[mi][ni][r] + bv;
                v = fmaxf(v, 0.f);
                v = fmaf(v, scale, shift);
                lds[(lrowb + r)*136 + lcol] = (f16_t)v;
            }
        }
    }
    __syncthreads();
    // coalesced store: 16 lanes cover one row's 256 B
#pragma unroll
    for (int it = 0; it < 8; ++it) {
        int row = it*16 + (t >> 4);
        int ch  = t & 15;
        uint4 v = *(const uint4*)&lds[row*136 + ch*8];
        *(uint4*)(C + (size_t)(r0 + row)*N + n0 + ch*8) = v;
    }
}

// ---------------- segment scatter (each segment has exactly 32 atoms) ----------------
__global__ void scatter_k(const int* __restrict__ mem, int* __restrict__ counts, int* __restrict__ slots) {
    int i = blockIdx.x * 256 + threadIdx.x;   // 65536 exact
    int s = mem[i];
    int p = atomicAdd(&counts[s], 1);
    if (p < 32) slots[s*32 + p] = i;
}

// ---------------- segment sum/max over H3[65536x512] f16 -> fp = tanh([ssum|smax]) ----------------
__global__ __launch_bounds__(256)
void reduce_k(const f16_t* __restrict__ H3, const int* __restrict__ counts,
              const int* __restrict__ slots, float* __restrict__ fp) {
    int s = blockIdx.x, t = threadIdx.x;
    int cnt = counts[s]; if (cnt > 32) cnt = 32;
    float s0 = 0.f, s1 = 0.f, m0 = -INFINITY, m1 = -INFINITY;
    for (int i = 0; i < cnt; ++i) {
        int a = slots[s*32 + i];
        const f16_t* hr = H3 + (size_t)a*512;
        float v0 = (float)hr[t], v1 = (float)hr[t+256];
        s0 += v0; s1 += v1;
        m0 = fmaxf(m0, v0); m1 = fmaxf(m1, v1);
    }
    float* fr = fp + (size_t)s*1024;
    fr[t]       = tanhf(s0);
    fr[t+256]   = tanhf(s1);
    fr[512+t]   = tanhf(m0);
    fr[768+t]   = tanhf(m1);
}

// ---------------- logits = fp @ out_w + out_b; probs = softmax(pairs) ----------------
__global__ __launch_bounds__(256)
void final_k(const float* __restrict__ fp, const float* __restrict__ out_w,
             const float* __restrict__ out_b, float* __restrict__ probs, float* __restrict__ logits) {
    __shared__ float row[1024];
    __shared__ float lg[24];
    int s = blockIdx.x, t = threadIdx.x;
    const float* fr = fp + (size_t)s*1024;
    *(float4*)&row[t*4] = *(const float4*)&fr[t*4];
    __syncthreads();
    if (t < 192) {
        int o = t >> 3;
        int k0 = (t & 7) * 128;
        float acc = 0.f;
        for (int k = 0; k < 128; ++k)
            acc = fmaf(row[k0+k], out_w[(size_t)(k0+k)*24 + o], acc);
        acc += __shfl_xor(acc, 1);
        acc += __shfl_xor(acc, 2);
        acc += __shfl_xor(acc, 4);
        if ((t & 7) == 0) lg[o] = acc + out_b[o];
    }
    __syncthreads();
    if (t < 12) {
        float l0 = lg[2*t], l1 = lg[2*t+1];
        float m = fmaxf(l0, l1);
        float e0 = expf(l0-m), e1 = expf(l1-m);
        float inv = 1.f / (e0 + e1);
        int base = s*24 + 2*t;
        probs[base]   = e0*inv;  probs[base+1]  = e1*inv;
        logits[base]  = l0;      logits[base+1] = l1;
    }
}

extern "C" void kernel_launch(void* const* d_in, const int* in_sizes, int n_in,
                              void* d_out, int out_size, void* d_ws, size_t ws_size,
                              hipStream_t stream) {
    const float* atom       = (const float*)d_in[0];
    const int*   membership = (const int*)  d_in[2];
    Adj adj;
    for (int d = 0; d < 10; ++d) adj.p[d] = (const int*)d_in[4+d];
    const float* gc1_w0     = (const float*)d_in[14];
    const float* gc1_wself  = (const float*)d_in[15];
    const float* gc1_wneigh = (const float*)d_in[16];
    const float* gc1_b      = (const float*)d_in[17];
    const float* gc2_w0     = (const float*)d_in[18];
    const float* gc2_wself  = (const float*)d_in[19];
    const float* gc2_wneigh = (const float*)d_in[20];
    const float* gc2_b      = (const float*)d_in[21];
    const float* bn1g = (const float*)d_in[22]; const float* bn1b = (const float*)d_in[23];
    const float* bn1m = (const float*)d_in[24]; const float* bn1v = (const float*)d_in[25];
    const float* bn2g = (const float*)d_in[26]; const float* bn2b = (const float*)d_in[27];
    const float* bn2m = (const float*)d_in[28]; const float* bn2v = (const float*)d_in[29];
    const float* bn3g = (const float*)d_in[30]; const float* bn3b = (const float*)d_in[31];
    const float* bn3m = (const float*)d_in[32]; const float* bn3v = (const float*)d_in[33];
    const float* dense_w = (const float*)d_in[34];
    const float* dense_b = (const float*)d_in[35];
    const float* out_w   = (const float*)d_in[36];
    const float* out_b   = (const float*)d_in[37];

    // workspace layout in f16 elements (2 B each); aliasing:
    //   H2 = H1 (H1 dead after pool1-read... reused after pool2 source dead);
    //   P2 = NB2 slot (NB2 dead after gemm2); H3 = H1+P1 span (both dead by gemm3)
    f16_t* wsb = (f16_t*)d_ws;
    f16_t* xq   = wsb;                       //  6,291,456
    f16_t* NBX  = wsb + 6291456;             //  6,291,456
    f16_t* H1b  = wsb + 12582912;            // 16,777,216
    f16_t* P1b  = wsb + 29360128;            // 16,777,216
    f16_t* NB2b = wsb + 46137344;            // 16,777,216
    f16_t* H2b  = H1b;
    f16_t* P2b  = NB2b;
    f16_t* H3b  = H1b;                       // 33,554,432 spans H1+P1
    f16_t* W1p  = wsb + 62914560;            //    540,672
    f16_t* W2p  = wsb + 63455232;            //  1,441,792
    f16_t* Wdp  = wsb + 64897024;            //    131,072
    int*  counts = (int*)(wsb + 65028096);   // 2048 ints
    int*  slots  = counts + 2048;            // 65536 ints

    float* outp   = (float*)d_out;
    float* probs  = outp;            // 2048*24
    float* logits = outp + 49152;    // 2048*24
    float* fp     = outp + 98304;    // 2048*1024

    // weight packing
    pack_w1<<<2112, 256, 0, stream>>>(gc1_w0, gc1_wself, gc1_wneigh, W1p);
    pack_w2<<<5632, 256, 0, stream>>>(gc2_w0, gc2_wself, gc2_wneigh, W2p);
    pack_wd<<<512,  256, 0, stream>>>(dense_w, Wdp);

    // gc1: xq (self, k<96) + NBX (neigh, k>=96)
    cvt_pad<<<(NATOMS*96)/256, 256, 0, stream>>>(atom, xq);
    nbsum_x<<<(NATOMS*12)/256, 256, 0, stream>>>(xq, NBX, adj);
    gemm_mfma<192,96,96,256,2,true><<<1024, 256, 0, stream>>>(
        xq, NBX, W1p, gc1_b, bn1g, bn1b, bn1m, bn1v, H1b);
    pool_k<<<(NATOMS*32)/256, 256, 0, stream>>>(H1b, P1b, adj);

    // gc2
    nbsum_k<<<(NATOMS*32)/256, 256, 0, stream>>>(P1b, NB2b, adj);
    gemm_mfma<512,256,256,256,2,true><<<1024, 256, 0, stream>>>(
        P1b, NB2b, W2p, gc2_b, bn2g, bn2b, bn2m, bn2v, H2b);
    pool_k<<<(NATOMS*32)/256, 256, 0, stream>>>(H2b, P2b, adj);

    // dense
    gemm_mfma<256,256,256,512,4,false><<<2048, 256, 0, stream>>>(
        P2b, P2b, Wdp, dense_b, bn3g, bn3b, bn3m, bn3v, H3b);

    // segment reduce + tanh -> fp
    hipMemsetAsync((void*)counts, 0, 2048*sizeof(int), stream);
    scatter_k<<<NATOMS/256, 256, 0, stream>>>(membership, counts, slots);
    reduce_k<<<2048, 256, 0, stream>>>(H3b, counts, slots, fp);

    // readout
    final_k<<<2048, 256, 0, stream>>>(fp, out_w, out_b, probs, logits);
}